// Round 10
// baseline (307.396 us; speedup 1.0000x reference)
//
#include <hip/hip_runtime.h>
#include <hip/hip_bf16.h>

#define BB 8
#define CC 512
#define SS 64
#define TT 128
#define DD 256
#define PP 8
#define BS (BB*SS)            // 512
#define NSTAT (BB*CC*SS)      // 262144
#define EPSV 1e-5f

typedef float f32x4 __attribute__((ext_vector_type(4)));
typedef __bf16 bf16x8 __attribute__((ext_vector_type(8)));

__device__ __forceinline__ unsigned short f2bf(float f) {
  unsigned u = __float_as_uint(f);
  u += 0x7FFFu + ((u >> 16) & 1u);
  return (unsigned short)(u >> 16);
}
__device__ __forceinline__ float bf2f(unsigned short h) {
  return __uint_as_float(((unsigned)h) << 16);
}

// ---- K1: per-block BN partials (transposed, no atomics) + bf16 stash of x. grid 2048 ----
__global__ __launch_bounds__(256) void k1_stats(const float* __restrict__ x,
    float* __restrict__ csum_part, float* __restrict__ ssq_part,
    unsigned short* __restrict__ xbf) {
  int bid = blockIdx.x;
  int bs = bid >> 2, cq = bid & 3;
  int b = bs >> 6, s = bs & 63;
  const float* xb = x + ((size_t)b * CC * SS + s) * TT;
  unsigned short* xo = xbf + ((size_t)b * CC * SS + s) * TT;
  int tid = threadIdx.x;
  int t4 = tid & 31, coff = tid >> 5;
  float cs0=0,cs1=0,cs2=0,cs3=0, ss0=0,ss1=0,ss2=0,ss3=0;
  #pragma unroll 8
  for (int k = 0; k < 16; k++) {
    int c = cq*128 + coff + k*8;
    float4 v = *reinterpret_cast<const float4*>(xb + (size_t)c*(SS*TT) + t4*4);
    ushort4 o; o.x=f2bf(v.x); o.y=f2bf(v.y); o.z=f2bf(v.z); o.w=f2bf(v.w);
    *reinterpret_cast<ushort4*>(xo + (size_t)c*(SS*TT) + t4*4) = o;
    cs0 += v.x; cs1 += v.y; cs2 += v.z; cs3 += v.w;
    ss0 += v.x*v.x; ss1 += v.y*v.y; ss2 += v.z*v.z; ss3 += v.w*v.w;
  }
  __shared__ float4 redC[256];
  __shared__ float4 redS[256];
  redC[tid] = make_float4(cs0,cs1,cs2,cs3);
  redS[tid] = make_float4(ss0,ss1,ss2,ss3);
  __syncthreads();
  if (tid < 32) {
    #pragma unroll
    for (int j = 1; j < 8; j++) {
      float4 a = redC[tid + j*32], bq = redS[tid + j*32];
      cs0+=a.x; cs1+=a.y; cs2+=a.z; cs3+=a.w;
      ss0+=bq.x; ss1+=bq.y; ss2+=bq.z; ss3+=bq.w;
    }
    int t0 = tid*4;
    csum_part[(size_t)(t0+0)*2048 + bid] = cs0;
    csum_part[(size_t)(t0+1)*2048 + bid] = cs1;
    csum_part[(size_t)(t0+2)*2048 + bid] = cs2;
    csum_part[(size_t)(t0+3)*2048 + bid] = cs3;
    ssq_part[(size_t)(t0+0)*2048 + bid] = ss0;
    ssq_part[(size_t)(t0+1)*2048 + bid] = ss1;
    ssq_part[(size_t)(t0+2)*2048 + bid] = ss2;
    ssq_part[(size_t)(t0+3)*2048 + bid] = ss3;
  }
}

// ---- K1b: reduce partials -> sumt/sumsq. grid 128 ----
__global__ __launch_bounds__(256) void k1b_reduce(
    const float* __restrict__ csum_part, const float* __restrict__ ssq_part,
    float* __restrict__ sumt, float* __restrict__ sumsq) {
  int t = blockIdx.x, tid = threadIdx.x;
  const float* cp = csum_part + (size_t)t*2048;
  const float* sp = ssq_part + (size_t)t*2048;
  float cs = 0.f, ss = 0.f;
  #pragma unroll
  for (int k=0;k<8;k++) { cs += cp[tid + k*256]; ss += sp[tid + k*256]; }
  #pragma unroll
  for (int off=32; off; off>>=1) { cs += __shfl_xor(cs,off); ss += __shfl_xor(ss,off); }
  __shared__ float redc[4], reds[4];
  int wave = tid >> 6, lane = tid & 63;
  if (lane == 0) { redc[wave] = cs; reds[wave] = ss; }
  __syncthreads();
  if (tid == 0) {
    sumt[t]  = redc[0]+redc[1]+redc[2]+redc[3];
    sumsq[t] = reds[0]+reds[1]+reds[2]+reds[3];
  }
}

// ---- K2: route1 -> w1out fp32 (unscaled) + w1bf = g*w1 (BN folded) + b1' quarter. grid 2048 ----
__global__ __launch_bounds__(256) void k2_route1(
    const float* __restrict__ sumt, const float* __restrict__ sumsq,
    const float* __restrict__ csum_part, const float* __restrict__ gamma,
    const float* __restrict__ beta, const float* __restrict__ keys1,
    const float* __restrict__ Wp1, const float* __restrict__ bp1,
    float* __restrict__ w1out, unsigned short* __restrict__ w1bf,
    float* __restrict__ b1) {
  int bid = blockIdx.x;
  int bs = bid >> 2, q = bid & 3;
  int tid = threadIdx.x;
  __shared__ float a1s[PP];
  __shared__ float g_s[TT], h_s[TT];
  __shared__ float db_s[64];
  if (tid < TT) {
    float m = sumt[tid] * (1.f/NSTAT);
    float var = sumsq[tid]*(1.f/NSTAT) - m*m;
    float g = gamma[tid] * rsqrtf(var + EPSV);
    g_s[tid] = g;
    h_s[tid] = beta[tid] - m*g;   // y = x*g + h
  }
  if (tid < 64) {
    float pv0, pv1;
    {
      int t = tid;
      float4 c4v = *reinterpret_cast<const float4*>(csum_part + (size_t)t*2048 + bs*4);
      float cs = c4v.x + c4v.y + c4v.z + c4v.w;
      float m = sumt[t] * (1.f/NSTAT);
      float var = sumsq[t]*(1.f/NSTAT) - m*m;
      float g = gamma[t] * rsqrtf(var + EPSV);
      pv0 = (cs*(1.f/CC) - m)*g + beta[t];
    }
    {
      int t = tid + 64;
      float4 c4v = *reinterpret_cast<const float4*>(csum_part + (size_t)t*2048 + bs*4);
      float cs = c4v.x + c4v.y + c4v.z + c4v.w;
      float m = sumt[t] * (1.f/NSTAT);
      float var = sumsq[t]*(1.f/NSTAT) - m*m;
      float g = gamma[t] * rsqrtf(var + EPSV);
      pv1 = (cs*(1.f/CC) - m)*g + beta[t];
    }
    float ssq = pv0*pv0 + pv1*pv1;
    #pragma unroll
    for (int off=32; off; off>>=1) ssq += __shfl_xor(ssq, off);
    float pn = sqrtf(ssq) + 1e-8f;
    float lg[PP];
    #pragma unroll
    for (int p=0;p<PP;p++) {
      float k0 = keys1[p*TT + tid], k1 = keys1[p*TT + tid + 64];
      float dot = pv0*k0 + pv1*k1;
      float kn = k0*k0 + k1*k1;
      #pragma unroll
      for (int off=32; off; off>>=1) { dot += __shfl_xor(dot,off); kn += __shfl_xor(kn,off); }
      lg[p] = dot / (pn * (sqrtf(kn) + 1e-8f));
    }
    if (tid == 0) {
      float mx = lg[0];
      #pragma unroll
      for (int p=1;p<PP;p++) mx = fmaxf(mx, lg[p]);
      float se = 0.f, e[PP];
      #pragma unroll
      for (int p=0;p<PP;p++){ e[p] = __expf(lg[p]-mx); se += e[p]; }
      float inv = 1.f/se;
      #pragma unroll
      for (int p=0;p<PP;p++) a1s[p] = e[p]*inv;
    }
  }
  __syncthreads();
  float a[PP];
  #pragma unroll
  for (int p=0;p<PP;p++) a[p]=a1s[p];
  #pragma unroll
  for (int i=0;i<8;i++) {
    int idx = tid + i*256;
    int dr = idx >> 5, c4 = idx & 31;
    size_t roff = (size_t)(q*64+dr)*TT + c4*4;
    size_t off = (size_t)bs*(DD*TT) + roff;
    float4 accv = make_float4(0.f,0.f,0.f,0.f);
    #pragma unroll
    for (int p=0;p<PP;p++) {
      float4 v = *reinterpret_cast<const float4*>(Wp1 + (size_t)p*(DD*TT) + roff);
      accv.x += a[p]*v.x; accv.y += a[p]*v.y; accv.z += a[p]*v.z; accv.w += a[p]*v.w;
    }
    *reinterpret_cast<float4*>(w1out + off) = accv;        // unscaled (reference output)
    float4 gv = *reinterpret_cast<const float4*>(g_s + c4*4);
    ushort4 o;
    o.x=f2bf(accv.x*gv.x); o.y=f2bf(accv.y*gv.y);
    o.z=f2bf(accv.z*gv.z); o.w=f2bf(accv.w*gv.w);
    *reinterpret_cast<ushort4*>(w1bf + off) = o;           // BN-folded shadow
    float4 hv = *reinterpret_cast<const float4*>(h_s + c4*4);
    float pd = accv.x*hv.x + accv.y*hv.y + accv.z*hv.z + accv.w*hv.w;
    #pragma unroll
    for (int off2=16; off2; off2>>=1) pd += __shfl_xor(pd, off2);
    if (c4 == 0) db_s[dr] = pd;                            // Σ_t h[t]*w1[d,t]
  }
  __syncthreads();
  if (tid < 64) {
    int d = q*64 + tid;
    float bacc = db_s[tid];
    #pragma unroll
    for (int p=0;p<PP;p++) bacc += a[p]*bp1[p*DD + d];
    b1[(size_t)bs*DD + d] = bacc;                          // b1' (BN bias folded)
  }
}

// ---- K3: pool-only GEMM1: p2part = colsum over relu(xbf @ w1bf^T + b1'). grid 2048, 512 thr ----
__global__ __launch_bounds__(512) void k3_pool(
    const unsigned short* __restrict__ xbf, const unsigned short* __restrict__ w1bf,
    const float* __restrict__ b1, float* __restrict__ p2part) {
  int bid = blockIdx.x;
  int bs = bid >> 2, mt = bid & 3;
  int b = bs >> 6, s = bs & 63;
  __shared__ unsigned short lA[128*128];   // 32 KB, row 256 B, swizzled
  __shared__ unsigned short lB[256*128];   // 64 KB, row 256 B, swizzled
  int tid = threadIdx.x;
  char* lAc = reinterpret_cast<char*>(lA);
  char* lBc = reinterpret_cast<char*>(lB);
  const unsigned short* xb = xbf + (((size_t)b*CC + mt*128)*SS + s)*TT;
  #pragma unroll
  for (int i=0;i<4;i++) {
    int flat = tid + i*512;
    int r = flat >> 4, c8 = flat & 15;
    uint4 v = *reinterpret_cast<const uint4*>(xb + (size_t)r*(SS*TT) + c8*8);
    unsigned addr = (unsigned)(r*256) + (((unsigned)(c8*16)) ^ (((unsigned)(r&7))<<4));
    *reinterpret_cast<uint4*>(lAc + addr) = v;
  }
  const unsigned short* wsrc = w1bf + (size_t)bs*(DD*TT);
  #pragma unroll
  for (int i=0;i<8;i++) {
    int flat = tid + i*512;
    int n = flat >> 4, ch = flat & 15;
    uint4 v = *reinterpret_cast<const uint4*>(wsrc + (size_t)flat*8);
    unsigned addr = (unsigned)(n*256) + (((unsigned)(ch*16)) ^ (((unsigned)(n&7))<<4));
    *reinterpret_cast<uint4*>(lBc + addr) = v;
  }
  __syncthreads();
  int wave = tid >> 6, lane = tid & 63;
  int wm = wave >> 2, wn = wave & 3;     // 2 x 4 waves, per-wave tile 64x64
  int lr = lane & 15, kg = lane >> 4;
  f32x4 zero = {0.f,0.f,0.f,0.f};
  f32x4 acc[4][4];
  #pragma unroll
  for (int m=0;m<4;m++)
    #pragma unroll
    for (int n=0;n<4;n++) acc[m][n] = zero;
  #pragma unroll
  for (int k0=0;k0<128;k0+=32) {
    bf16x8 af[4], bfr[4];
    #pragma unroll
    for (int m=0;m<4;m++) {
      int row = wm*64 + m*16 + lr;
      unsigned addr = (unsigned)(row*256) + (((unsigned)(k0*2 + kg*16)) ^ (((unsigned)(row&7))<<4));
      af[m] = *reinterpret_cast<const bf16x8*>(lAc + addr);
    }
    #pragma unroll
    for (int n=0;n<4;n++) {
      int row = wn*64 + n*16 + lr;
      unsigned addr = (unsigned)(row*256) + (((unsigned)(k0*2 + kg*16)) ^ (((unsigned)(row&7))<<4));
      bfr[n] = *reinterpret_cast<const bf16x8*>(lBc + addr);
    }
    #pragma unroll
    for (int m=0;m<4;m++)
      #pragma unroll
      for (int n=0;n<4;n++)
        acc[m][n] = __builtin_amdgcn_mfma_f32_16x16x32_bf16(af[m], bfr[n], acc[m][n], 0, 0, 0);
  }
  const float* b1p = b1 + (size_t)bs*DD;
  float* p2p = p2part + (((size_t)bid*2) + wm)*DD;
  #pragma unroll
  for (int n=0;n<4;n++) {
    int d = wn*64 + n*16 + lr;
    float bv = b1p[d];
    float csum = 0.f;
    #pragma unroll
    for (int m=0;m<4;m++) {
      #pragma unroll
      for (int j=0;j<4;j++) {
        csum += fmaxf(acc[m][n][j] + bv, 0.f);
      }
    }
    csum += __shfl_xor(csum, 16);
    csum += __shfl_xor(csum, 32);
    if (kg == 0) p2p[d] = csum;
  }
}

// ---- K4: route2 -> a2 (redundant per q), write w2out fp32 + w2bf + b2 quarter. grid 2048 ----
__global__ __launch_bounds__(256) void k4_route2(
    const float* __restrict__ p2part, const float* __restrict__ keys2,
    const float* __restrict__ Wp2, const float* __restrict__ bp2,
    float* __restrict__ w2out, unsigned short* __restrict__ w2bf,
    float* __restrict__ b2) {
  int bid = blockIdx.x;
  int bs = bid >> 2, q = bid & 3;
  int tid = threadIdx.x;
  __shared__ float a2s[PP];
  if (tid < 64) {
    float pv[4]; float ssq = 0.f;
    #pragma unroll
    for (int j=0;j<4;j++) {
      int d = tid + 64*j;
      float s8 = 0.f;
      #pragma unroll
      for (int r=0;r<8;r++) s8 += p2part[((size_t)bs*8 + r)*DD + d];
      pv[j] = s8 * (1.f/CC);
      ssq += pv[j]*pv[j];
    }
    #pragma unroll
    for (int off=32; off; off>>=1) ssq += __shfl_xor(ssq, off);
    float pn = sqrtf(ssq) + 1e-8f;
    float lg[PP];
    #pragma unroll
    for (int p=0;p<PP;p++) {
      float dot = 0.f, kn = 0.f;
      #pragma unroll
      for (int j=0;j<4;j++) {
        int d = tid + 64*j;
        float kv = keys2[p*DD + d];
        dot += pv[j]*kv; kn += kv*kv;
      }
      #pragma unroll
      for (int off=32; off; off>>=1) { dot += __shfl_xor(dot,off); kn += __shfl_xor(kn,off); }
      lg[p] = dot / (pn * (sqrtf(kn)+1e-8f));
    }
    if (tid == 0) {
      float mx = lg[0];
      #pragma unroll
      for (int p=1;p<PP;p++) mx = fmaxf(mx,lg[p]);
      float se=0.f, e[PP];
      #pragma unroll
      for (int p=0;p<PP;p++){ e[p]=__expf(lg[p]-mx); se+=e[p]; }
      float inv = 1.f/se;
      #pragma unroll
      for (int p=0;p<PP;p++) a2s[p]=e[p]*inv;
    }
  }
  __syncthreads();
  float a[PP];
  #pragma unroll
  for (int p=0;p<PP;p++) a[p]=a2s[p];
  #pragma unroll
  for (int i=0;i<8;i++) {
    int idx = tid + i*256;
    int tr = idx >> 6, c4 = idx & 63;
    size_t roff = (size_t)(q*32+tr)*DD + c4*4;
    size_t off = (size_t)bs*(TT*DD) + roff;
    float4 accv = make_float4(0.f,0.f,0.f,0.f);
    #pragma unroll
    for (int p=0;p<PP;p++) {
      float4 v = *reinterpret_cast<const float4*>(Wp2 + (size_t)p*(TT*DD) + roff);
      accv.x += a[p]*v.x; accv.y += a[p]*v.y; accv.z += a[p]*v.z; accv.w += a[p]*v.w;
    }
    *reinterpret_cast<float4*>(w2out + off) = accv;
    ushort4 o; o.x=f2bf(accv.x); o.y=f2bf(accv.y); o.z=f2bf(accv.z); o.w=f2bf(accv.w);
    *reinterpret_cast<ushort4*>(w2bf + off) = o;
  }
  if (tid < 32) {
    int t = q*32 + tid;
    float bacc = 0.f;
    #pragma unroll
    for (int p=0;p<PP;p++) bacc += a[p]*bp2[p*TT + t];
    b2[(size_t)bs*TT + t] = bacc;
  }
}

// ---- K5: fused z-recompute + GEMM2: out = x + relu(x@w1^T+b1')@w2^T + b2.
//      grid 2048, 1024 thr, 160 KB LDS ----
__global__ __launch_bounds__(1024, 4) void k5_fused(
    const unsigned short* __restrict__ xbf, const unsigned short* __restrict__ w1bf,
    const unsigned short* __restrict__ w2bf, const float* __restrict__ b1,
    const float* __restrict__ b2, float* __restrict__ out) {
  int bid = blockIdx.x;
  int bs = bid >> 2, mt = bid & 3;
  int b = bs >> 6, s = bs & 63;
  __shared__ __align__(16) char smem[163840];
  char* lX  = smem;            // 32 KB: x-tile [128 c][128 t], row 256 B, swz
  char* lW  = smem + 32768;    // 64 KB: w1 [256 d][128 t] row 256 B; later z [128 c][256 d] row 512 B
  char* lW2 = smem + 98304;    // 64 KB: w2 [128 t][256 d], row 512 B, swz
  int tid = threadIdx.x;
  const unsigned short* xb  = xbf  + (((size_t)b*CC + mt*128)*SS + s)*TT;
  const unsigned short* w1p = w1bf + (size_t)bs*(DD*TT);
  const unsigned short* w2p = w2bf + (size_t)bs*(TT*DD);
  // stage x + w1 into LDS now
  #pragma unroll
  for (int i=0;i<2;i++) {
    int flat = tid + i*1024;
    int r = flat >> 4, ch = flat & 15;
    uint4 v = *reinterpret_cast<const uint4*>(xb + (size_t)r*(SS*TT) + ch*8);
    unsigned addr = (unsigned)(r*256) + (((unsigned)(ch*16)) ^ (((unsigned)(r&7))<<4));
    *reinterpret_cast<uint4*>(lX + addr) = v;
  }
  #pragma unroll
  for (int i=0;i<4;i++) {
    int flat = tid + i*1024;
    int r = flat >> 4, ch = flat & 15;
    uint4 v = *reinterpret_cast<const uint4*>(w1p + (size_t)flat*8);
    unsigned addr = (unsigned)(r*256) + (((unsigned)(ch*16)) ^ (((unsigned)(r&7))<<4));
    *reinterpret_cast<uint4*>(lW + addr) = v;
  }
  // issue w2 loads; LDS write deferred (streams under GEMM1)
  uint4 tw2[4];
  #pragma unroll
  for (int i=0;i<4;i++) {
    int flat = tid + i*1024;
    tw2[i] = *reinterpret_cast<const uint4*>(w2p + (size_t)flat*8);
  }
  int wave = tid >> 6, lane = tid & 63;
  int lr = lane & 15, kg = lane >> 4;
  // GEMM1 mapping: 16 waves = 2(m) x 8(n); wave tile 64 c x 32 d
  int wm1 = wave >> 3, wn1 = wave & 7;
  // b1' values for this lane's two d-fragments (global read, L2-hot)
  const float* b1p = b1 + (size_t)bs*DD;
  float b1v0 = b1p[wn1*32 + 0*16 + lr];
  float b1v1 = b1p[wn1*32 + 1*16 + lr];
  __syncthreads();
  f32x4 zero = {0.f,0.f,0.f,0.f};
  f32x4 acc1[4][2];
  #pragma unroll
  for (int m=0;m<4;m++)
    #pragma unroll
    for (int n=0;n<2;n++) acc1[m][n] = zero;
  #pragma unroll
  for (int k0=0;k0<128;k0+=32) {
    bf16x8 af[4], bfr[2];
    #pragma unroll
    for (int m=0;m<4;m++) {
      int row = wm1*64 + m*16 + lr;
      unsigned addr = (unsigned)(row*256) + (((unsigned)(k0*2 + kg*16)) ^ (((unsigned)(row&7))<<4));
      af[m] = *reinterpret_cast<const bf16x8*>(lX + addr);
    }
    #pragma unroll
    for (int n=0;n<2;n++) {
      int row = wn1*32 + n*16 + lr;
      unsigned addr = (unsigned)(row*256) + (((unsigned)(k0*2 + kg*16)) ^ (((unsigned)(row&7))<<4));
      bfr[n] = *reinterpret_cast<const bf16x8*>(lW + addr);
    }
    #pragma unroll
    for (int m=0;m<4;m++)
      #pragma unroll
      for (int n=0;n<2;n++)
        acc1[m][n] = __builtin_amdgcn_mfma_f32_16x16x32_bf16(af[m], bfr[n], acc1[m][n], 0, 0, 0);
  }
  // write w2 to its (distinct) LDS region — waits only on w2's vmcnt
  #pragma unroll
  for (int i=0;i<4;i++) {
    int flat = tid + i*1024;
    int r = flat >> 5, ch = flat & 31;
    unsigned addr = (unsigned)(r*512) + (((unsigned)(ch*16)) ^ (((unsigned)(r&7))<<4));
    *reinterpret_cast<uint4*>(lW2 + addr) = tw2[i];
  }
  __syncthreads();   // all GEMM1 reads of lW done; w2 in place
  // z = relu(acc1 + b1') -> bf16 -> lW region as [128 c][256 d], row 512 B, swz
  #pragma unroll
  for (int n=0;n<2;n++) {
    int d = wn1*32 + n*16 + lr;
    float bv = (n == 0) ? b1v0 : b1v1;
    #pragma unroll
    for (int m=0;m<4;m++) {
      int rbase = wm1*64 + m*16 + kg*4;
      #pragma unroll
      for (int j=0;j<4;j++) {
        int row = rbase + j;
        float v = fmaxf(acc1[m][n][j] + bv, 0.f);
        unsigned addr = (unsigned)(row*512) + (((unsigned)(d*2)) ^ (((unsigned)(row&7))<<4));
        *reinterpret_cast<unsigned short*>(lW + addr) = f2bf(v);
      }
    }
  }
  __syncthreads();
  // GEMM2 mapping: 16 waves = 4(m) x 4(n); wave tile 32 c x 32 t; K=256 over d
  int wm2 = wave >> 2, wn2 = wave & 3;
  f32x4 acc2[2][2];
  #pragma unroll
  for (int m=0;m<2;m++)
    #pragma unroll
    for (int n=0;n<2;n++) acc2[m][n] = zero;
  #pragma unroll
  for (int k0=0;k0<256;k0+=32) {
    bf16x8 af[2], bfr[2];
    #pragma unroll
    for (int m=0;m<2;m++) {
      int row = wm2*32 + m*16 + lr;
      unsigned addr = (unsigned)(row*512) + (((unsigned)(k0*2 + kg*16)) ^ (((unsigned)(row&7))<<4));
      af[m] = *reinterpret_cast<const bf16x8*>(lW + addr);
    }
    #pragma unroll
    for (int n=0;n<2;n++) {
      int row = wn2*32 + n*16 + lr;
      unsigned addr = (unsigned)(row*512) + (((unsigned)(k0*2 + kg*16)) ^ (((unsigned)(row&7))<<4));
      bfr[n] = *reinterpret_cast<const bf16x8*>(lW2 + addr);
    }
    #pragma unroll
    for (int m=0;m<2;m++)
      #pragma unroll
      for (int n=0;n<2;n++)
        acc2[m][n] = __builtin_amdgcn_mfma_f32_16x16x32_bf16(af[m], bfr[n], acc2[m][n], 0, 0, 0);
  }
  // epilogue: out = acc2 + b2 + x (residual from lX)
  const float* b2p = b2 + (size_t)bs*TT;
  float* ob = out + (((size_t)b*CC + mt*128)*SS + s)*TT;
  #pragma unroll
  for (int n=0;n<2;n++) {
    int t = wn2*32 + n*16 + lr;
    float bv = b2p[t];
    #pragma unroll
    for (int m=0;m<2;m++) {
      int rbase = wm2*32 + m*16 + kg*4;
      #pragma unroll
      for (int j=0;j<4;j++) {
        int row = rbase + j;
        unsigned xaddr = (unsigned)(row*256) + (((unsigned)(t*2)) ^ (((unsigned)(row&7))<<4));
        float xv = bf2f(*reinterpret_cast<const unsigned short*>(lX + xaddr));
        ob[(size_t)row*(SS*TT) + t] = acc2[m][n][j] + bv + xv;
      }
    }
  }
}

extern "C" void kernel_launch(void* const* d_in, const int* in_sizes, int n_in,
                              void* d_out, int out_size, void* d_ws, size_t ws_size,
                              hipStream_t stream) {
  (void)in_sizes; (void)n_in; (void)out_size; (void)ws_size;
  const float* x     = (const float*)d_in[0];
  const float* gamma = (const float*)d_in[1];
  const float* beta  = (const float*)d_in[2];
  const float* keys1 = (const float*)d_in[3];
  const float* Wp1   = (const float*)d_in[4];
  const float* bp1   = (const float*)d_in[5];
  const float* keys2 = (const float*)d_in[6];
  const float* Wp2   = (const float*)d_in[7];
  const float* bp2   = (const float*)d_in[8];
  float* out = (float*)d_out;
  char* ws = (char*)d_ws;

  // ws layout (bytes):
  float* sumt        = (float*)(ws + 0);              // 512 B
  float* sumsq       = (float*)(ws + 512);            // 512 B
  float* csum_part   = (float*)(ws + 1024);           // 1 MB (128 x 2048, transposed)
  float* ssq_part    = (float*)(ws + 1049600);        // 1 MB
  float* p2part      = (float*)(ws + 2098176);        // 4 MB (512 x 8 x 256)
  float* b1          = (float*)(ws + 6292480);        // 512 KB
  float* b2          = (float*)(ws + 6816768);        // 256 KB
  unsigned short* w1bf = (unsigned short*)(ws + 7078912);   // 33.5 MB
  unsigned short* w2bf = (unsigned short*)(ws + 40633344);  // 33.5 MB
  unsigned short* xbf  = (unsigned short*)(ws + 74187776);  // 67 MB -> end ~141 MB

  float* w1out = out + 33554432;
  float* w2out = out + 50331648;

  k1_stats  <<<BS*4, 256,  0, stream>>>(x, csum_part, ssq_part, xbf);
  k1b_reduce<<<TT,   256,  0, stream>>>(csum_part, ssq_part, sumt, sumsq);
  k2_route1 <<<BS*4, 256,  0, stream>>>(sumt, sumsq, csum_part, gamma, beta, keys1, Wp1, bp1,
                                        w1out, w1bf, b1);
  k3_pool   <<<BS*4, 512,  0, stream>>>(xbf, w1bf, b1, p2part);
  k4_route2 <<<BS*4, 256,  0, stream>>>(p2part, keys2, Wp2, bp2, w2out, w2bf, b2);
  k5_fused  <<<BS*4, 1024, 0, stream>>>(xbf, w1bf, w2bf, b1, b2, out);
}

// Round 11
// 291.769 us; speedup vs baseline: 1.0536x; 1.0536x over previous
//
#include <hip/hip_runtime.h>
#include <hip/hip_bf16.h>

#define BB 8
#define CC 512
#define SS 64
#define TT 128
#define DD 256
#define PP 8
#define BS (BB*SS)            // 512
#define NSTAT (BB*CC*SS)      // 262144
#define EPSV 1e-5f

typedef float f32x4 __attribute__((ext_vector_type(4)));
typedef __bf16 bf16x8 __attribute__((ext_vector_type(8)));

__device__ __forceinline__ unsigned short f2bf(float f) {
  unsigned u = __float_as_uint(f);
  u += 0x7FFFu + ((u >> 16) & 1u);
  return (unsigned short)(u >> 16);
}
__device__ __forceinline__ float bf2f(unsigned short h) {
  return __uint_as_float(((unsigned)h) << 16);
}

// ---- K1: per-block BN partials (transposed, no atomics) + bf16 stash of x. grid 2048 ----
__global__ __launch_bounds__(256) void k1_stats(const float* __restrict__ x,
    float* __restrict__ csum_part, float* __restrict__ ssq_part,
    unsigned short* __restrict__ xbf) {
  int bid = blockIdx.x;
  int bs = bid >> 2, cq = bid & 3;
  int b = bs >> 6, s = bs & 63;
  const float* xb = x + ((size_t)b * CC * SS + s) * TT;
  unsigned short* xo = xbf + ((size_t)b * CC * SS + s) * TT;
  int tid = threadIdx.x;
  int t4 = tid & 31, coff = tid >> 5;
  float cs0=0,cs1=0,cs2=0,cs3=0, ss0=0,ss1=0,ss2=0,ss3=0;
  #pragma unroll 8
  for (int k = 0; k < 16; k++) {
    int c = cq*128 + coff + k*8;
    float4 v = *reinterpret_cast<const float4*>(xb + (size_t)c*(SS*TT) + t4*4);
    ushort4 o; o.x=f2bf(v.x); o.y=f2bf(v.y); o.z=f2bf(v.z); o.w=f2bf(v.w);
    *reinterpret_cast<ushort4*>(xo + (size_t)c*(SS*TT) + t4*4) = o;
    cs0 += v.x; cs1 += v.y; cs2 += v.z; cs3 += v.w;
    ss0 += v.x*v.x; ss1 += v.y*v.y; ss2 += v.z*v.z; ss3 += v.w*v.w;
  }
  __shared__ float4 redC[256];
  __shared__ float4 redS[256];
  redC[tid] = make_float4(cs0,cs1,cs2,cs3);
  redS[tid] = make_float4(ss0,ss1,ss2,ss3);
  __syncthreads();
  if (tid < 32) {
    #pragma unroll
    for (int j = 1; j < 8; j++) {
      float4 a = redC[tid + j*32], bq = redS[tid + j*32];
      cs0+=a.x; cs1+=a.y; cs2+=a.z; cs3+=a.w;
      ss0+=bq.x; ss1+=bq.y; ss2+=bq.z; ss3+=bq.w;
    }
    int t0 = tid*4;
    csum_part[(size_t)(t0+0)*2048 + bid] = cs0;
    csum_part[(size_t)(t0+1)*2048 + bid] = cs1;
    csum_part[(size_t)(t0+2)*2048 + bid] = cs2;
    csum_part[(size_t)(t0+3)*2048 + bid] = cs3;
    ssq_part[(size_t)(t0+0)*2048 + bid] = ss0;
    ssq_part[(size_t)(t0+1)*2048 + bid] = ss1;
    ssq_part[(size_t)(t0+2)*2048 + bid] = ss2;
    ssq_part[(size_t)(t0+3)*2048 + bid] = ss3;
  }
}

// ---- K1b: reduce partials -> sumt/sumsq. grid 128 ----
__global__ __launch_bounds__(256) void k1b_reduce(
    const float* __restrict__ csum_part, const float* __restrict__ ssq_part,
    float* __restrict__ sumt, float* __restrict__ sumsq) {
  int t = blockIdx.x, tid = threadIdx.x;
  const float* cp = csum_part + (size_t)t*2048;
  const float* sp = ssq_part + (size_t)t*2048;
  float cs = 0.f, ss = 0.f;
  #pragma unroll
  for (int k=0;k<8;k++) { cs += cp[tid + k*256]; ss += sp[tid + k*256]; }
  #pragma unroll
  for (int off=32; off; off>>=1) { cs += __shfl_xor(cs,off); ss += __shfl_xor(ss,off); }
  __shared__ float redc[4], reds[4];
  int wave = tid >> 6, lane = tid & 63;
  if (lane == 0) { redc[wave] = cs; reds[wave] = ss; }
  __syncthreads();
  if (tid == 0) {
    sumt[t]  = redc[0]+redc[1]+redc[2]+redc[3];
    sumsq[t] = reds[0]+reds[1]+reds[2]+reds[3];
  }
}

// ---- K2: route1 -> a1 (redundant per q), write w1out fp32 + w1bf + b1 quarter. grid 2048 ----
__global__ __launch_bounds__(256) void k2_route1(
    const float* __restrict__ sumt, const float* __restrict__ sumsq,
    const float* __restrict__ csum_part, const float* __restrict__ gamma,
    const float* __restrict__ beta, const float* __restrict__ keys1,
    const float* __restrict__ Wp1, const float* __restrict__ bp1,
    float* __restrict__ w1out, unsigned short* __restrict__ w1bf,
    float* __restrict__ b1) {
  int bid = blockIdx.x;
  int bs = bid >> 2, q = bid & 3;
  int tid = threadIdx.x;
  __shared__ float a1s[PP];
  if (tid < 64) {
    float pv0, pv1;
    {
      int t = tid;
      float4 c4v = *reinterpret_cast<const float4*>(csum_part + (size_t)t*2048 + bs*4);
      float cs = c4v.x + c4v.y + c4v.z + c4v.w;
      float m = sumt[t] * (1.f/NSTAT);
      float var = sumsq[t]*(1.f/NSTAT) - m*m;
      float g = gamma[t] * rsqrtf(var + EPSV);
      pv0 = (cs*(1.f/CC) - m)*g + beta[t];
    }
    {
      int t = tid + 64;
      float4 c4v = *reinterpret_cast<const float4*>(csum_part + (size_t)t*2048 + bs*4);
      float cs = c4v.x + c4v.y + c4v.z + c4v.w;
      float m = sumt[t] * (1.f/NSTAT);
      float var = sumsq[t]*(1.f/NSTAT) - m*m;
      float g = gamma[t] * rsqrtf(var + EPSV);
      pv1 = (cs*(1.f/CC) - m)*g + beta[t];
    }
    float ssq = pv0*pv0 + pv1*pv1;
    #pragma unroll
    for (int off=32; off; off>>=1) ssq += __shfl_xor(ssq, off);
    float pn = sqrtf(ssq) + 1e-8f;
    float lg[PP];
    #pragma unroll
    for (int p=0;p<PP;p++) {
      float k0 = keys1[p*TT + tid], k1 = keys1[p*TT + tid + 64];
      float dot = pv0*k0 + pv1*k1;
      float kn = k0*k0 + k1*k1;
      #pragma unroll
      for (int off=32; off; off>>=1) { dot += __shfl_xor(dot,off); kn += __shfl_xor(kn,off); }
      lg[p] = dot / (pn * (sqrtf(kn) + 1e-8f));
    }
    if (tid == 0) {
      float mx = lg[0];
      #pragma unroll
      for (int p=1;p<PP;p++) mx = fmaxf(mx, lg[p]);
      float se = 0.f, e[PP];
      #pragma unroll
      for (int p=0;p<PP;p++){ e[p] = __expf(lg[p]-mx); se += e[p]; }
      float inv = 1.f/se;
      #pragma unroll
      for (int p=0;p<PP;p++) a1s[p] = e[p]*inv;
    }
  }
  __syncthreads();
  float a[PP];
  #pragma unroll
  for (int p=0;p<PP;p++) a[p]=a1s[p];
  #pragma unroll
  for (int i=0;i<8;i++) {
    int idx = tid + i*256;
    int dr = idx >> 5, c4 = idx & 31;
    size_t roff = (size_t)(q*64+dr)*TT + c4*4;
    size_t off = (size_t)bs*(DD*TT) + roff;
    float4 accv = make_float4(0.f,0.f,0.f,0.f);
    #pragma unroll
    for (int p=0;p<PP;p++) {
      float4 v = *reinterpret_cast<const float4*>(Wp1 + (size_t)p*(DD*TT) + roff);
      accv.x += a[p]*v.x; accv.y += a[p]*v.y; accv.z += a[p]*v.z; accv.w += a[p]*v.w;
    }
    *reinterpret_cast<float4*>(w1out + off) = accv;
    ushort4 o; o.x=f2bf(accv.x); o.y=f2bf(accv.y); o.z=f2bf(accv.z); o.w=f2bf(accv.w);
    *reinterpret_cast<ushort4*>(w1bf + off) = o;
  }
  if (tid < 64) {
    int d = q*64 + tid;
    float bacc = 0.f;
    #pragma unroll
    for (int p=0;p<PP;p++) bacc += a[p]*bp1[p*DD + d];
    b1[(size_t)bs*DD + d] = bacc;
  }
}

// ---- K3: GEMM1 Z = relu(BN(x) @ W1^T + b1), + pooled2 partials. grid 2048, 512 thr.
//      XCD-swizzled: 4 mt-blocks of a bs land on the same XCD (panel L2 reuse) ----
__global__ __launch_bounds__(512) void k3_gemm1(
    const unsigned short* __restrict__ xbf, const float* __restrict__ sumt,
    const float* __restrict__ sumsq, const float* __restrict__ gamma,
    const float* __restrict__ beta, const unsigned short* __restrict__ w1bf,
    const float* __restrict__ b1, unsigned short* __restrict__ zbf,
    float* __restrict__ p2part) {
  int j = blockIdx.x;
  int xcd = j & 7, r = j >> 3;        // HW round-robins blockIdx%8 across XCDs
  int bs = xcd*64 + (r >> 2);
  int mt = r & 3;
  int bid = bs*4 + mt;                // logical id for p2part indexing
  int b = bs >> 6, s = bs & 63;
  __shared__ unsigned short lA[128*128];   // 32 KB, row 256 B, swizzled
  __shared__ unsigned short lB[256*128];   // 64 KB, row 256 B, swizzled; reused for z-tile
  __shared__ float mean_s[TT], g_s[TT], beta_s[TT];
  int tid = threadIdx.x;
  if (tid < TT) {
    float m = sumt[tid]*(1.f/NSTAT);
    float var = sumsq[tid]*(1.f/NSTAT) - m*m;
    mean_s[tid] = m;
    g_s[tid] = gamma[tid]*rsqrtf(var+EPSV);
    beta_s[tid] = beta[tid];
  }
  __syncthreads();
  char* lAc = reinterpret_cast<char*>(lA);
  char* lBc = reinterpret_cast<char*>(lB);
  auto bn2 = [&](unsigned pair, int t0) -> unsigned {
    float lo = bf2f((unsigned short)(pair & 0xFFFFu));
    float hi = bf2f((unsigned short)(pair >> 16));
    lo = (lo - mean_s[t0])*g_s[t0] + beta_s[t0];
    hi = (hi - mean_s[t0+1])*g_s[t0+1] + beta_s[t0+1];
    return ((unsigned)f2bf(hi) << 16) | (unsigned)f2bf(lo);
  };
  const unsigned short* xb = xbf + (((size_t)b*CC + mt*128)*SS + s)*TT;
  #pragma unroll
  for (int i=0;i<4;i++) {
    int flat = tid + i*512;
    int rr = flat >> 4, c8 = flat & 15;
    int t0 = c8*8;
    uint4 v = *reinterpret_cast<const uint4*>(xb + (size_t)rr*(SS*TT) + t0);
    uint4 o;
    o.x = bn2(v.x, t0); o.y = bn2(v.y, t0+2); o.z = bn2(v.z, t0+4); o.w = bn2(v.w, t0+6);
    unsigned addr = (unsigned)(rr*256) + (((unsigned)(c8*16)) ^ (((unsigned)(rr&7))<<4));
    *reinterpret_cast<uint4*>(lAc + addr) = o;
  }
  const unsigned short* wsrc = w1bf + (size_t)bs*(DD*TT);
  #pragma unroll
  for (int i=0;i<8;i++) {
    int flat = tid + i*512;
    int n = flat >> 4, ch = flat & 15;
    uint4 v = *reinterpret_cast<const uint4*>(wsrc + (size_t)flat*8);
    unsigned addr = (unsigned)(n*256) + (((unsigned)(ch*16)) ^ (((unsigned)(n&7))<<4));
    *reinterpret_cast<uint4*>(lBc + addr) = v;
  }
  __syncthreads();
  int wave = tid >> 6, lane = tid & 63;
  int wm = wave >> 2, wn = wave & 3;     // 2 x 4 waves, per-wave tile 64x64
  int lr = lane & 15, kg = lane >> 4;
  f32x4 zero = {0.f,0.f,0.f,0.f};
  f32x4 acc[4][4];
  #pragma unroll
  for (int m=0;m<4;m++)
    #pragma unroll
    for (int n=0;n<4;n++) acc[m][n] = zero;
  #pragma unroll
  for (int k0=0;k0<128;k0+=32) {
    bf16x8 af[4], bfr[4];
    #pragma unroll
    for (int m=0;m<4;m++) {
      int row = wm*64 + m*16 + lr;
      unsigned addr = (unsigned)(row*256) + (((unsigned)(k0*2 + kg*16)) ^ (((unsigned)(row&7))<<4));
      af[m] = *reinterpret_cast<const bf16x8*>(lAc + addr);
    }
    #pragma unroll
    for (int n=0;n<4;n++) {
      int row = wn*64 + n*16 + lr;
      unsigned addr = (unsigned)(row*256) + (((unsigned)(k0*2 + kg*16)) ^ (((unsigned)(row&7))<<4));
      bfr[n] = *reinterpret_cast<const bf16x8*>(lBc + addr);
    }
    #pragma unroll
    for (int m=0;m<4;m++)
      #pragma unroll
      for (int n=0;n<4;n++)
        acc[m][n] = __builtin_amdgcn_mfma_f32_16x16x32_bf16(af[m], bfr[n], acc[m][n], 0, 0, 0);
  }
  const float* b1p = b1 + (size_t)bs*DD;
  float* p2p = p2part + (((size_t)bid*2) + wm)*DD;
  __syncthreads();   // everyone done reading lB
  #pragma unroll
  for (int n=0;n<4;n++) {
    int d = wn*64 + n*16 + lr;
    float bv = b1p[d];
    float csum = 0.f;
    #pragma unroll
    for (int m=0;m<4;m++) {
      int rbase = wm*64 + m*16 + kg*4;
      #pragma unroll
      for (int jj=0;jj<4;jj++) {
        float v = fmaxf(acc[m][n][jj] + bv, 0.f);
        lB[(rbase+jj)*DD + d] = f2bf(v);   // z-tile [128][256]
        csum += v;
      }
    }
    csum += __shfl_xor(csum, 16);
    csum += __shfl_xor(csum, 32);
    if (kg == 0) p2p[d] = csum;
  }
  __syncthreads();
  unsigned short* zb = zbf + (((size_t)b*CC + mt*128)*SS + s)*DD;
  #pragma unroll
  for (int i=0;i<8;i++) {
    int flat = tid + i*512;
    int rr = flat >> 5, ch = flat & 31;
    uint4 v = *reinterpret_cast<const uint4*>(lBc + flat*16);
    *reinterpret_cast<uint4*>(zb + (size_t)rr*(SS*DD) + ch*8) = v;
  }
}

// ---- K4: route2 -> a2 (redundant per q), write w2out fp32 + w2bf + b2 quarter. grid 2048 ----
__global__ __launch_bounds__(256) void k4_route2(
    const float* __restrict__ p2part, const float* __restrict__ keys2,
    const float* __restrict__ Wp2, const float* __restrict__ bp2,
    float* __restrict__ w2out, unsigned short* __restrict__ w2bf,
    float* __restrict__ b2) {
  int bid = blockIdx.x;
  int bs = bid >> 2, q = bid & 3;
  int tid = threadIdx.x;
  __shared__ float a2s[PP];
  if (tid < 64) {
    float pv[4]; float ssq = 0.f;
    #pragma unroll
    for (int j=0;j<4;j++) {
      int d = tid + 64*j;
      float s8 = 0.f;
      #pragma unroll
      for (int r=0;r<8;r++) s8 += p2part[((size_t)bs*8 + r)*DD + d];
      pv[j] = s8 * (1.f/CC);
      ssq += pv[j]*pv[j];
    }
    #pragma unroll
    for (int off=32; off; off>>=1) ssq += __shfl_xor(ssq, off);
    float pn = sqrtf(ssq) + 1e-8f;
    float lg[PP];
    #pragma unroll
    for (int p=0;p<PP;p++) {
      float dot = 0.f, kn = 0.f;
      #pragma unroll
      for (int j=0;j<4;j++) {
        int d = tid + 64*j;
        float kv = keys2[p*DD + d];
        dot += pv[j]*kv; kn += kv*kv;
      }
      #pragma unroll
      for (int off=32; off; off>>=1) { dot += __shfl_xor(dot,off); kn += __shfl_xor(kn,off); }
      lg[p] = dot / (pn * (sqrtf(kn)+1e-8f));
    }
    if (tid == 0) {
      float mx = lg[0];
      #pragma unroll
      for (int p=1;p<PP;p++) mx = fmaxf(mx,lg[p]);
      float se=0.f, e[PP];
      #pragma unroll
      for (int p=0;p<PP;p++){ e[p]=__expf(lg[p]-mx); se+=e[p]; }
      float inv = 1.f/se;
      #pragma unroll
      for (int p=0;p<PP;p++) a2s[p]=e[p]*inv;
    }
  }
  __syncthreads();
  float a[PP];
  #pragma unroll
  for (int p=0;p<PP;p++) a[p]=a2s[p];
  #pragma unroll
  for (int i=0;i<8;i++) {
    int idx = tid + i*256;
    int tr = idx >> 6, c4 = idx & 63;
    size_t roff = (size_t)(q*32+tr)*DD + c4*4;
    size_t off = (size_t)bs*(TT*DD) + roff;
    float4 accv = make_float4(0.f,0.f,0.f,0.f);
    #pragma unroll
    for (int p=0;p<PP;p++) {
      float4 v = *reinterpret_cast<const float4*>(Wp2 + (size_t)p*(TT*DD) + roff);
      accv.x += a[p]*v.x; accv.y += a[p]*v.y; accv.z += a[p]*v.z; accv.w += a[p]*v.w;
    }
    *reinterpret_cast<float4*>(w2out + off) = accv;
    ushort4 o; o.x=f2bf(accv.x); o.y=f2bf(accv.y); o.z=f2bf(accv.z); o.w=f2bf(accv.w);
    *reinterpret_cast<ushort4*>(w2bf + off) = o;
  }
  if (tid < 32) {
    int t = q*32 + tid;
    float bacc = 0.f;
    #pragma unroll
    for (int p=0;p<PP;p++) bacc += a[p]*bp2[p*TT + t];
    b2[(size_t)bs*TT + t] = bacc;
  }
}

// ---- K5: GEMM2 out = x + Z @ W2^T + b2. grid 2048, 512 thr, XCD-swizzled ----
__global__ __launch_bounds__(512) void k5_gemm2(
    const unsigned short* __restrict__ zbf, const unsigned short* __restrict__ w2bf,
    const float* __restrict__ b2, const unsigned short* __restrict__ xbf,
    float* __restrict__ out) {
  int j = blockIdx.x;
  int xcd = j & 7, r = j >> 3;
  int bs = xcd*64 + (r >> 2);
  int mt = r & 3;
  int b = bs >> 6, s = bs & 63;
  __shared__ unsigned short lA[128*256];   // 64 KB, row 512 B, swizzled
  __shared__ unsigned short lB[128*256];   // 64 KB, row 512 B, swizzled
  int tid = threadIdx.x;
  char* lAc = reinterpret_cast<char*>(lA);
  char* lBc = reinterpret_cast<char*>(lB);
  const unsigned short* za = zbf + (((size_t)b*CC + mt*128)*SS + s)*DD;
  #pragma unroll
  for (int i=0;i<8;i++) {
    int flat = tid + i*512;
    int rr = flat >> 5, ch = flat & 31;
    uint4 v = *reinterpret_cast<const uint4*>(za + (size_t)rr*(SS*DD) + ch*8);
    unsigned addr = (unsigned)(rr*512) + (((unsigned)(ch*16)) ^ (((unsigned)(rr&7))<<4));
    *reinterpret_cast<uint4*>(lAc + addr) = v;
  }
  const unsigned short* wsrc = w2bf + (size_t)bs*(TT*DD);
  #pragma unroll
  for (int i=0;i<8;i++) {
    int flat = tid + i*512;
    int rr = flat >> 5, ch = flat & 31;
    uint4 v = *reinterpret_cast<const uint4*>(wsrc + (size_t)flat*8);
    unsigned addr = (unsigned)(rr*512) + (((unsigned)(ch*16)) ^ (((unsigned)(rr&7))<<4));
    *reinterpret_cast<uint4*>(lBc + addr) = v;
  }
  __syncthreads();
  int wave = tid >> 6, lane = tid & 63;
  int wm = wave >> 2, wn = wave & 3;     // per-wave tile 64 x 32
  int lr = lane & 15, kg = lane >> 4;
  f32x4 zero = {0.f,0.f,0.f,0.f};
  f32x4 acc[4][2];
  #pragma unroll
  for (int m=0;m<4;m++)
    #pragma unroll
    for (int n=0;n<2;n++) acc[m][n] = zero;
  #pragma unroll
  for (int k0=0;k0<256;k0+=32) {
    bf16x8 af[4], bfr[2];
    #pragma unroll
    for (int m=0;m<4;m++) {
      int row = wm*64 + m*16 + lr;
      unsigned addr = (unsigned)(row*512) + (((unsigned)(k0*2 + kg*16)) ^ (((unsigned)(row&7))<<4));
      af[m] = *reinterpret_cast<const bf16x8*>(lAc + addr);
    }
    #pragma unroll
    for (int n=0;n<2;n++) {
      int row = wn*32 + n*16 + lr;
      unsigned addr = (unsigned)(row*512) + (((unsigned)(k0*2 + kg*16)) ^ (((unsigned)(row&7))<<4));
      bfr[n] = *reinterpret_cast<const bf16x8*>(lBc + addr);
    }
    #pragma unroll
    for (int m=0;m<4;m++)
      #pragma unroll
      for (int n=0;n<2;n++)
        acc[m][n] = __builtin_amdgcn_mfma_f32_16x16x32_bf16(af[m], bfr[n], acc[m][n], 0, 0, 0);
  }
  const float* b2p = b2 + (size_t)bs*TT;
  const unsigned short* xb = xbf + (((size_t)b*CC + mt*128)*SS + s)*TT;
  float* ob = out + (((size_t)b*CC + mt*128)*SS + s)*TT;
  #pragma unroll
  for (int n=0;n<2;n++) {
    int t = wn*32 + n*16 + lr;
    float bv = b2p[t];
    #pragma unroll
    for (int m=0;m<4;m++) {
      int rbase = wm*64 + m*16 + kg*4;
      #pragma unroll
      for (int jj=0;jj<4;jj++) {
        size_t off = (size_t)(rbase+jj)*(SS*TT) + t;
        ob[off] = acc[m][n][jj] + bv + bf2f(xb[off]);
      }
    }
  }
}

extern "C" void kernel_launch(void* const* d_in, const int* in_sizes, int n_in,
                              void* d_out, int out_size, void* d_ws, size_t ws_size,
                              hipStream_t stream) {
  (void)in_sizes; (void)n_in; (void)out_size; (void)ws_size;
  const float* x     = (const float*)d_in[0];
  const float* gamma = (const float*)d_in[1];
  const float* beta  = (const float*)d_in[2];
  const float* keys1 = (const float*)d_in[3];
  const float* Wp1   = (const float*)d_in[4];
  const float* bp1   = (const float*)d_in[5];
  const float* keys2 = (const float*)d_in[6];
  const float* Wp2   = (const float*)d_in[7];
  const float* bp2   = (const float*)d_in[8];
  float* out = (float*)d_out;
  char* ws = (char*)d_ws;

  // ws layout (bytes):
  float* sumt        = (float*)(ws + 0);              // 512 B
  float* sumsq       = (float*)(ws + 512);            // 512 B
  float* csum_part   = (float*)(ws + 1024);           // 1 MB (128 x 2048, transposed)
  float* ssq_part    = (float*)(ws + 1049600);        // 1 MB
  float* p2part      = (float*)(ws + 2098176);        // 4 MB (512 x 8 x 256)
  float* b1          = (float*)(ws + 6292480);        // 512 KB
  float* b2          = (float*)(ws + 6816768);        // 256 KB
  unsigned short* w1bf = (unsigned short*)(ws + 7078912);   // 33.5 MB
  unsigned short* w2bf = (unsigned short*)(ws + 40633344);  // 33.5 MB
  unsigned short* xbf  = (unsigned short*)(ws + 74187776);  // 67 MB
  unsigned short* zbf  = (unsigned short*)(ws + 141296640); // 134 MB -> end ~275 MB

  float* w1out = out + 33554432;
  float* w2out = out + 50331648;

  k1_stats  <<<BS*4, 256, 0, stream>>>(x, csum_part, ssq_part, xbf);
  k1b_reduce<<<TT,   256, 0, stream>>>(csum_part, ssq_part, sumt, sumsq);
  k2_route1 <<<BS*4, 256, 0, stream>>>(sumt, sumsq, csum_part, gamma, beta, keys1, Wp1, bp1,
                                       w1out, w1bf, b1);
  k3_gemm1  <<<BS*4, 512, 0, stream>>>(xbf, sumt, sumsq, gamma, beta, w1bf, b1, zbf, p2part);
  k4_route2 <<<BS*4, 256, 0, stream>>>(p2part, keys2, Wp2, bp2, w2out, w2bf, b2);
  k5_gemm2  <<<BS*4, 512, 0, stream>>>(zbf, w2bf, b2, xbf, out);
}

// Round 13
// 259.884 us; speedup vs baseline: 1.1828x; 1.1227x over previous
//
#include <hip/hip_runtime.h>
#include <hip/hip_bf16.h>

#define BB 8
#define CC 512
#define SS 64
#define TT 128
#define DD 256
#define PP 8
#define BS (BB*SS)            // 512
#define NSTAT (BB*CC*SS)      // 262144
#define EPSV 1e-5f

typedef float f32x4 __attribute__((ext_vector_type(4)));
typedef __bf16 bf16x8 __attribute__((ext_vector_type(8)));

__device__ __forceinline__ unsigned short f2bf(float f) {
  unsigned u = __float_as_uint(f);
  u += 0x7FFFu + ((u >> 16) & 1u);
  return (unsigned short)(u >> 16);
}
__device__ __forceinline__ float bf2f(unsigned short h) {
  return __uint_as_float(((unsigned)h) << 16);
}

// ---- K1: per-block BN partials (transposed, no atomics) + bf16 stash of x. grid 2048 ----
__global__ __launch_bounds__(256) void k1_stats(const float* __restrict__ x,
    float* __restrict__ csum_part, float* __restrict__ ssq_part,
    unsigned short* __restrict__ xbf) {
  int bid = blockIdx.x;
  int bs = bid >> 2, cq = bid & 3;
  int b = bs >> 6, s = bs & 63;
  const float* xb = x + ((size_t)b * CC * SS + s) * TT;
  unsigned short* xo = xbf + ((size_t)b * CC * SS + s) * TT;
  int tid = threadIdx.x;
  int t4 = tid & 31, coff = tid >> 5;
  float cs0=0,cs1=0,cs2=0,cs3=0, ss0=0,ss1=0,ss2=0,ss3=0;
  #pragma unroll 8
  for (int k = 0; k < 16; k++) {
    int c = cq*128 + coff + k*8;
    float4 v = *reinterpret_cast<const float4*>(xb + (size_t)c*(SS*TT) + t4*4);
    ushort4 o; o.x=f2bf(v.x); o.y=f2bf(v.y); o.z=f2bf(v.z); o.w=f2bf(v.w);
    *reinterpret_cast<ushort4*>(xo + (size_t)c*(SS*TT) + t4*4) = o;
    cs0 += v.x; cs1 += v.y; cs2 += v.z; cs3 += v.w;
    ss0 += v.x*v.x; ss1 += v.y*v.y; ss2 += v.z*v.z; ss3 += v.w*v.w;
  }
  __shared__ float4 redC[256];
  __shared__ float4 redS[256];
  redC[tid] = make_float4(cs0,cs1,cs2,cs3);
  redS[tid] = make_float4(ss0,ss1,ss2,ss3);
  __syncthreads();
  if (tid < 32) {
    #pragma unroll
    for (int j = 1; j < 8; j++) {
      float4 a = redC[tid + j*32], bq = redS[tid + j*32];
      cs0+=a.x; cs1+=a.y; cs2+=a.z; cs3+=a.w;
      ss0+=bq.x; ss1+=bq.y; ss2+=bq.z; ss3+=bq.w;
    }
    int t0 = tid*4;
    csum_part[(size_t)(t0+0)*2048 + bid] = cs0;
    csum_part[(size_t)(t0+1)*2048 + bid] = cs1;
    csum_part[(size_t)(t0+2)*2048 + bid] = cs2;
    csum_part[(size_t)(t0+3)*2048 + bid] = cs3;
    ssq_part[(size_t)(t0+0)*2048 + bid] = ss0;
    ssq_part[(size_t)(t0+1)*2048 + bid] = ss1;
    ssq_part[(size_t)(t0+2)*2048 + bid] = ss2;
    ssq_part[(size_t)(t0+3)*2048 + bid] = ss3;
  }
}

// ---- K1b: reduce partials -> sumt/sumsq. grid 128 ----
__global__ __launch_bounds__(256) void k1b_reduce(
    const float* __restrict__ csum_part, const float* __restrict__ ssq_part,
    float* __restrict__ sumt, float* __restrict__ sumsq) {
  int t = blockIdx.x, tid = threadIdx.x;
  const float* cp = csum_part + (size_t)t*2048;
  const float* sp = ssq_part + (size_t)t*2048;
  float cs = 0.f, ss = 0.f;
  #pragma unroll
  for (int k=0;k<8;k++) { cs += cp[tid + k*256]; ss += sp[tid + k*256]; }
  #pragma unroll
  for (int off=32; off; off>>=1) { cs += __shfl_xor(cs,off); ss += __shfl_xor(ss,off); }
  __shared__ float redc[4], reds[4];
  int wave = tid >> 6, lane = tid & 63;
  if (lane == 0) { redc[wave] = cs; reds[wave] = ss; }
  __syncthreads();
  if (tid == 0) {
    sumt[t]  = redc[0]+redc[1]+redc[2]+redc[3];
    sumsq[t] = reds[0]+reds[1]+reds[2]+reds[3];
  }
}

// ---- K2: route1 -> a1 (redundant per q), write w1out fp32 (nt) + w1bf + b1 quarter. grid 2048 ----
__global__ __launch_bounds__(256) void k2_route1(
    const float* __restrict__ sumt, const float* __restrict__ sumsq,
    const float* __restrict__ csum_part, const float* __restrict__ gamma,
    const float* __restrict__ beta, const float* __restrict__ keys1,
    const float* __restrict__ Wp1, const float* __restrict__ bp1,
    float* __restrict__ w1out, unsigned short* __restrict__ w1bf,
    float* __restrict__ b1) {
  int bid = blockIdx.x;
  int bs = bid >> 2, q = bid & 3;
  int tid = threadIdx.x;
  __shared__ float a1s[PP];
  if (tid < 64) {
    float pv0, pv1;
    {
      int t = tid;
      float4 c4v = *reinterpret_cast<const float4*>(csum_part + (size_t)t*2048 + bs*4);
      float cs = c4v.x + c4v.y + c4v.z + c4v.w;
      float m = sumt[t] * (1.f/NSTAT);
      float var = sumsq[t]*(1.f/NSTAT) - m*m;
      float g = gamma[t] * rsqrtf(var + EPSV);
      pv0 = (cs*(1.f/CC) - m)*g + beta[t];
    }
    {
      int t = tid + 64;
      float4 c4v = *reinterpret_cast<const float4*>(csum_part + (size_t)t*2048 + bs*4);
      float cs = c4v.x + c4v.y + c4v.z + c4v.w;
      float m = sumt[t] * (1.f/NSTAT);
      float var = sumsq[t]*(1.f/NSTAT) - m*m;
      float g = gamma[t] * rsqrtf(var + EPSV);
      pv1 = (cs*(1.f/CC) - m)*g + beta[t];
    }
    float ssq = pv0*pv0 + pv1*pv1;
    #pragma unroll
    for (int off=32; off; off>>=1) ssq += __shfl_xor(ssq, off);
    float pn = sqrtf(ssq) + 1e-8f;
    float lg[PP];
    #pragma unroll
    for (int p=0;p<PP;p++) {
      float k0 = keys1[p*TT + tid], k1 = keys1[p*TT + tid + 64];
      float dot = pv0*k0 + pv1*k1;
      float kn = k0*k0 + k1*k1;
      #pragma unroll
      for (int off=32; off; off>>=1) { dot += __shfl_xor(dot,off); kn += __shfl_xor(kn,off); }
      lg[p] = dot / (pn * (sqrtf(kn) + 1e-8f));
    }
    if (tid == 0) {
      float mx = lg[0];
      #pragma unroll
      for (int p=1;p<PP;p++) mx = fmaxf(mx, lg[p]);
      float se = 0.f, e[PP];
      #pragma unroll
      for (int p=0;p<PP;p++){ e[p] = __expf(lg[p]-mx); se += e[p]; }
      float inv = 1.f/se;
      #pragma unroll
      for (int p=0;p<PP;p++) a1s[p] = e[p]*inv;
    }
  }
  __syncthreads();
  float a[PP];
  #pragma unroll
  for (int p=0;p<PP;p++) a[p]=a1s[p];
  #pragma unroll
  for (int i=0;i<8;i++) {
    int idx = tid + i*256;
    int dr = idx >> 5, c4 = idx & 31;
    size_t roff = (size_t)(q*64+dr)*TT + c4*4;
    size_t off = (size_t)bs*(DD*TT) + roff;
    float4 accv = make_float4(0.f,0.f,0.f,0.f);
    #pragma unroll
    for (int p=0;p<PP;p++) {
      float4 v = *reinterpret_cast<const float4*>(Wp1 + (size_t)p*(DD*TT) + roff);
      accv.x += a[p]*v.x; accv.y += a[p]*v.y; accv.z += a[p]*v.z; accv.w += a[p]*v.w;
    }
    f32x4 nv = {accv.x, accv.y, accv.z, accv.w};
    __builtin_nontemporal_store(nv, reinterpret_cast<f32x4*>(w1out + off));
    ushort4 o; o.x=f2bf(accv.x); o.y=f2bf(accv.y); o.z=f2bf(accv.z); o.w=f2bf(accv.w);
    *reinterpret_cast<ushort4*>(w1bf + off) = o;
  }
  if (tid < 64) {
    int d = q*64 + tid;
    float bacc = 0.f;
    #pragma unroll
    for (int p=0;p<PP;p++) bacc += a[p]*bp1[p*DD + d];
    b1[(size_t)bs*DD + d] = bacc;
  }
}

// ---- K3: GEMM1 Z = relu(BN(x) @ W1^T + b1), + pooled2 partials. grid 2048, 512 thr.
//      XCD-swizzled: 4 mt-blocks of a bs land on the same XCD (panel L2 reuse) ----
__global__ __launch_bounds__(512) void k3_gemm1(
    const unsigned short* __restrict__ xbf, const float* __restrict__ sumt,
    const float* __restrict__ sumsq, const float* __restrict__ gamma,
    const float* __restrict__ beta, const unsigned short* __restrict__ w1bf,
    const float* __restrict__ b1, unsigned short* __restrict__ zbf,
    float* __restrict__ p2part) {
  int j = blockIdx.x;
  int xcd = j & 7, r = j >> 3;        // HW round-robins blockIdx%8 across XCDs
  int bs = xcd*64 + (r >> 2);
  int mt = r & 3;
  int bid = bs*4 + mt;                // logical id for p2part indexing
  int b = bs >> 6, s = bs & 63;
  __shared__ unsigned short lA[128*128];   // 32 KB, row 256 B, swizzled
  __shared__ unsigned short lB[256*128];   // 64 KB, row 256 B, swizzled; reused for z-tile
  __shared__ float mean_s[TT], g_s[TT], beta_s[TT];
  int tid = threadIdx.x;
  if (tid < TT) {
    float m = sumt[tid]*(1.f/NSTAT);
    float var = sumsq[tid]*(1.f/NSTAT) - m*m;
    mean_s[tid] = m;
    g_s[tid] = gamma[tid]*rsqrtf(var+EPSV);
    beta_s[tid] = beta[tid];
  }
  __syncthreads();
  char* lAc = reinterpret_cast<char*>(lA);
  char* lBc = reinterpret_cast<char*>(lB);
  auto bn2 = [&](unsigned pair, int t0) -> unsigned {
    float lo = bf2f((unsigned short)(pair & 0xFFFFu));
    float hi = bf2f((unsigned short)(pair >> 16));
    lo = (lo - mean_s[t0])*g_s[t0] + beta_s[t0];
    hi = (hi - mean_s[t0+1])*g_s[t0+1] + beta_s[t0+1];
    return ((unsigned)f2bf(hi) << 16) | (unsigned)f2bf(lo);
  };
  const unsigned short* xb = xbf + (((size_t)b*CC + mt*128)*SS + s)*TT;
  #pragma unroll
  for (int i=0;i<4;i++) {
    int flat = tid + i*512;
    int rr = flat >> 4, c8 = flat & 15;
    int t0 = c8*8;
    uint4 v = *reinterpret_cast<const uint4*>(xb + (size_t)rr*(SS*TT) + t0);
    uint4 o;
    o.x = bn2(v.x, t0); o.y = bn2(v.y, t0+2); o.z = bn2(v.z, t0+4); o.w = bn2(v.w, t0+6);
    unsigned addr = (unsigned)(rr*256) + (((unsigned)(c8*16)) ^ (((unsigned)(rr&7))<<4));
    *reinterpret_cast<uint4*>(lAc + addr) = o;
  }
  const unsigned short* wsrc = w1bf + (size_t)bs*(DD*TT);
  #pragma unroll
  for (int i=0;i<8;i++) {
    int flat = tid + i*512;
    int n = flat >> 4, ch = flat & 15;
    uint4 v = *reinterpret_cast<const uint4*>(wsrc + (size_t)flat*8);
    unsigned addr = (unsigned)(n*256) + (((unsigned)(ch*16)) ^ (((unsigned)(n&7))<<4));
    *reinterpret_cast<uint4*>(lBc + addr) = v;
  }
  __syncthreads();
  int wave = tid >> 6, lane = tid & 63;
  int wm = wave >> 2, wn = wave & 3;     // 2 x 4 waves, per-wave tile 64x64
  int lr = lane & 15, kg = lane >> 4;
  f32x4 zero = {0.f,0.f,0.f,0.f};
  f32x4 acc[4][4];
  #pragma unroll
  for (int m=0;m<4;m++)
    #pragma unroll
    for (int n=0;n<4;n++) acc[m][n] = zero;
  #pragma unroll
  for (int k0=0;k0<128;k0+=32) {
    bf16x8 af[4], bfr[4];
    #pragma unroll
    for (int m=0;m<4;m++) {
      int row = wm*64 + m*16 + lr;
      unsigned addr = (unsigned)(row*256) + (((unsigned)(k0*2 + kg*16)) ^ (((unsigned)(row&7))<<4));
      af[m] = *reinterpret_cast<const bf16x8*>(lAc + addr);
    }
    #pragma unroll
    for (int n=0;n<4;n++) {
      int row = wn*64 + n*16 + lr;
      unsigned addr = (unsigned)(row*256) + (((unsigned)(k0*2 + kg*16)) ^ (((unsigned)(row&7))<<4));
      bfr[n] = *reinterpret_cast<const bf16x8*>(lBc + addr);
    }
    #pragma unroll
    for (int m=0;m<4;m++)
      #pragma unroll
      for (int n=0;n<4;n++)
        acc[m][n] = __builtin_amdgcn_mfma_f32_16x16x32_bf16(af[m], bfr[n], acc[m][n], 0, 0, 0);
  }
  const float* b1p = b1 + (size_t)bs*DD;
  float* p2p = p2part + (((size_t)bid*2) + wm)*DD;
  __syncthreads();   // everyone done reading lB
  #pragma unroll
  for (int n=0;n<4;n++) {
    int d = wn*64 + n*16 + lr;
    float bv = b1p[d];
    float csum = 0.f;
    #pragma unroll
    for (int m=0;m<4;m++) {
      int rbase = wm*64 + m*16 + kg*4;
      #pragma unroll
      for (int jj=0;jj<4;jj++) {
        float v = fmaxf(acc[m][n][jj] + bv, 0.f);
        lB[(rbase+jj)*DD + d] = f2bf(v);   // z-tile [128][256]
        csum += v;
      }
    }
    csum += __shfl_xor(csum, 16);
    csum += __shfl_xor(csum, 32);
    if (kg == 0) p2p[d] = csum;
  }
  __syncthreads();
  unsigned short* zb = zbf + (((size_t)b*CC + mt*128)*SS + s)*DD;
  #pragma unroll
  for (int i=0;i<8;i++) {
    int flat = tid + i*512;
    int rr = flat >> 5, ch = flat & 31;
    uint4 v = *reinterpret_cast<const uint4*>(lBc + flat*16);
    *reinterpret_cast<uint4*>(zb + (size_t)rr*(SS*DD) + ch*8) = v;
  }
}

// ---- K4: route2 -> a2 (redundant per q), write w2out fp32 (nt) + w2bf + b2 quarter. grid 2048 ----
__global__ __launch_bounds__(256) void k4_route2(
    const float* __restrict__ p2part, const float* __restrict__ keys2,
    const float* __restrict__ Wp2, const float* __restrict__ bp2,
    float* __restrict__ w2out, unsigned short* __restrict__ w2bf,
    float* __restrict__ b2) {
  int bid = blockIdx.x;
  int bs = bid >> 2, q = bid & 3;
  int tid = threadIdx.x;
  __shared__ float a2s[PP];
  if (tid < 64) {
    float pv[4]; float ssq = 0.f;
    #pragma unroll
    for (int j=0;j<4;j++) {
      int d = tid + 64*j;
      float s8 = 0.f;
      #pragma unroll
      for (int r=0;r<8;r++) s8 += p2part[((size_t)bs*8 + r)*DD + d];
      pv[j] = s8 * (1.f/CC);
      ssq += pv[j]*pv[j];
    }
    #pragma unroll
    for (int off=32; off; off>>=1) ssq += __shfl_xor(ssq, off);
    float pn = sqrtf(ssq) + 1e-8f;
    float lg[PP];
    #pragma unroll
    for (int p=0;p<PP;p++) {
      float dot = 0.f, kn = 0.f;
      #pragma unroll
      for (int j=0;j<4;j++) {
        int d = tid + 64*j;
        float kv = keys2[p*DD + d];
        dot += pv[j]*kv; kn += kv*kv;
      }
      #pragma unroll
      for (int off=32; off; off>>=1) { dot += __shfl_xor(dot,off); kn += __shfl_xor(kn,off); }
      lg[p] = dot / (pn * (sqrtf(kn)+1e-8f));
    }
    if (tid == 0) {
      float mx = lg[0];
      #pragma unroll
      for (int p=1;p<PP;p++) mx = fmaxf(mx,lg[p]);
      float se=0.f, e[PP];
      #pragma unroll
      for (int p=0;p<PP;p++){ e[p]=__expf(lg[p]-mx); se+=e[p]; }
      float inv = 1.f/se;
      #pragma unroll
      for (int p=0;p<PP;p++) a2s[p]=e[p]*inv;
    }
  }
  __syncthreads();
  float a[PP];
  #pragma unroll
  for (int p=0;p<PP;p++) a[p]=a2s[p];
  #pragma unroll
  for (int i=0;i<8;i++) {
    int idx = tid + i*256;
    int tr = idx >> 6, c4 = idx & 63;
    size_t roff = (size_t)(q*32+tr)*DD + c4*4;
    size_t off = (size_t)bs*(TT*DD) + roff;
    float4 accv = make_float4(0.f,0.f,0.f,0.f);
    #pragma unroll
    for (int p=0;p<PP;p++) {
      float4 v = *reinterpret_cast<const float4*>(Wp2 + (size_t)p*(TT*DD) + roff);
      accv.x += a[p]*v.x; accv.y += a[p]*v.y; accv.z += a[p]*v.z; accv.w += a[p]*v.w;
    }
    f32x4 nv = {accv.x, accv.y, accv.z, accv.w};
    __builtin_nontemporal_store(nv, reinterpret_cast<f32x4*>(w2out + off));
    ushort4 o; o.x=f2bf(accv.x); o.y=f2bf(accv.y); o.z=f2bf(accv.z); o.w=f2bf(accv.w);
    *reinterpret_cast<ushort4*>(w2bf + off) = o;
  }
  if (tid < 32) {
    int t = q*32 + tid;
    float bacc = 0.f;
    #pragma unroll
    for (int p=0;p<PP;p++) bacc += a[p]*bp2[p*TT + t];
    b2[(size_t)bs*TT + t] = bacc;
  }
}

// ---- K5: GEMM2 out = x + Z @ W2^T + b2. grid 2048, 512 thr, XCD-swizzled, nt out-stores ----
__global__ __launch_bounds__(512) void k5_gemm2(
    const unsigned short* __restrict__ zbf, const unsigned short* __restrict__ w2bf,
    const float* __restrict__ b2, const unsigned short* __restrict__ xbf,
    float* __restrict__ out) {
  int j = blockIdx.x;
  int xcd = j & 7, r = j >> 3;
  int bs = xcd*64 + (r >> 2);
  int mt = r & 3;
  int b = bs >> 6, s = bs & 63;
  __shared__ unsigned short lA[128*256];   // 64 KB, row 512 B, swizzled
  __shared__ unsigned short lB[128*256];   // 64 KB, row 512 B, swizzled
  int tid = threadIdx.x;
  char* lAc = reinterpret_cast<char*>(lA);
  char* lBc = reinterpret_cast<char*>(lB);
  const unsigned short* za = zbf + (((size_t)b*CC + mt*128)*SS + s)*DD;
  #pragma unroll
  for (int i=0;i<8;i++) {
    int flat = tid + i*512;
    int rr = flat >> 5, ch = flat & 31;
    uint4 v = *reinterpret_cast<const uint4*>(za + (size_t)rr*(SS*DD) + ch*8);
    unsigned addr = (unsigned)(rr*512) + (((unsigned)(ch*16)) ^ (((unsigned)(rr&7))<<4));
    *reinterpret_cast<uint4*>(lAc + addr) = v;
  }
  const unsigned short* wsrc = w2bf + (size_t)bs*(TT*DD);
  #pragma unroll
  for (int i=0;i<8;i++) {
    int flat = tid + i*512;
    int rr = flat >> 5, ch = flat & 31;
    uint4 v = *reinterpret_cast<const uint4*>(wsrc + (size_t)flat*8);
    unsigned addr = (unsigned)(rr*512) + (((unsigned)(ch*16)) ^ (((unsigned)(rr&7))<<4));
    *reinterpret_cast<uint4*>(lBc + addr) = v;
  }
  __syncthreads();
  int wave = tid >> 6, lane = tid & 63;
  int wm = wave >> 2, wn = wave & 3;     // per-wave tile 64 x 32
  int lr = lane & 15, kg = lane >> 4;
  f32x4 zero = {0.f,0.f,0.f,0.f};
  f32x4 acc[4][2];
  #pragma unroll
  for (int m=0;m<4;m++)
    #pragma unroll
    for (int n=0;n<2;n++) acc[m][n] = zero;
  #pragma unroll
  for (int k0=0;k0<256;k0+=32) {
    bf16x8 af[4], bfr[2];
    #pragma unroll
    for (int m=0;m<4;m++) {
      int row = wm*64 + m*16 + lr;
      unsigned addr = (unsigned)(row*512) + (((unsigned)(k0*2 + kg*16)) ^ (((unsigned)(row&7))<<4));
      af[m] = *reinterpret_cast<const bf16x8*>(lAc + addr);
    }
    #pragma unroll
    for (int n=0;n<2;n++) {
      int row = wn*32 + n*16 + lr;
      unsigned addr = (unsigned)(row*512) + (((unsigned)(k0*2 + kg*16)) ^ (((unsigned)(row&7))<<4));
      bfr[n] = *reinterpret_cast<const bf16x8*>(lBc + addr);
    }
    #pragma unroll
    for (int m=0;m<4;m++)
      #pragma unroll
      for (int n=0;n<2;n++)
        acc[m][n] = __builtin_amdgcn_mfma_f32_16x16x32_bf16(af[m], bfr[n], acc[m][n], 0, 0, 0);
  }
  const float* b2p = b2 + (size_t)bs*TT;
  const unsigned short* xb = xbf + (((size_t)b*CC + mt*128)*SS + s)*TT;
  float* ob = out + (((size_t)b*CC + mt*128)*SS + s)*TT;
  #pragma unroll
  for (int n=0;n<2;n++) {
    int t = wn*32 + n*16 + lr;
    float bv = b2p[t];
    #pragma unroll
    for (int m=0;m<4;m++) {
      int rbase = wm*64 + m*16 + kg*4;
      #pragma unroll
      for (int jj=0;jj<4;jj++) {
        size_t off = (size_t)(rbase+jj)*(SS*TT) + t;
        __builtin_nontemporal_store(acc[m][n][jj] + bv + bf2f(xb[off]), ob + off);
      }
    }
  }
}

extern "C" void kernel_launch(void* const* d_in, const int* in_sizes, int n_in,
                              void* d_out, int out_size, void* d_ws, size_t ws_size,
                              hipStream_t stream) {
  (void)in_sizes; (void)n_in; (void)out_size; (void)ws_size;
  const float* x     = (const float*)d_in[0];
  const float* gamma = (const float*)d_in[1];
  const float* beta  = (const float*)d_in[2];
  const float* keys1 = (const float*)d_in[3];
  const float* Wp1   = (const float*)d_in[4];
  const float* bp1   = (const float*)d_in[5];
  const float* keys2 = (const float*)d_in[6];
  const float* Wp2   = (const float*)d_in[7];
  const float* bp2   = (const float*)d_in[8];
  float* out = (float*)d_out;
  char* ws = (char*)d_ws;

  // ws layout (bytes):
  float* sumt        = (float*)(ws + 0);              // 512 B
  float* sumsq       = (float*)(ws + 512);            // 512 B
  float* csum_part   = (float*)(ws + 1024);           // 1 MB (128 x 2048, transposed)
  float* ssq_part    = (float*)(ws + 1049600);        // 1 MB
  float* p2part      = (float*)(ws + 2098176);        // 4 MB (512 x 8 x 256)
  float* b1          = (float*)(ws + 6292480);        // 512 KB
  float* b2          = (float*)(ws + 6816768);        // 256 KB
  unsigned short* w1bf = (unsigned short*)(ws + 7078912);   // 33.5 MB
  unsigned short* w2bf = (unsigned short*)(ws + 40633344);  // 33.5 MB
  unsigned short* xbf  = (unsigned short*)(ws + 74187776);  // 67 MB
  unsigned short* zbf  = (unsigned short*)(ws + 141296640); // 134 MB -> end ~275 MB

  float* w1out = out + 33554432;
  float* w2out = out + 50331648;

  k1_stats  <<<BS*4, 256, 0, stream>>>(x, csum_part, ssq_part, xbf);
  k1b_reduce<<<TT,   256, 0, stream>>>(csum_part, ssq_part, sumt, sumsq);
  k2_route1 <<<BS*4, 256, 0, stream>>>(sumt, sumsq, csum_part, gamma, beta, keys1, Wp1, bp1,
                                       w1out, w1bf, b1);
  k3_gemm1  <<<BS*4, 512, 0, stream>>>(xbf, sumt, sumsq, gamma, beta, w1bf, b1, zbf, p2part);
  k4_route2 <<<BS*4, 256, 0, stream>>>(p2part, keys2, Wp2, bp2, w2out, w2bf, b2);
  k5_gemm2  <<<BS*4, 512, 0, stream>>>(zbf, w2bf, b2, xbf, out);
}